// Round 4
// baseline (21177.080 us; speedup 1.0000x reference)
//
#include <hip/hip_runtime.h>
#include <math.h>

namespace {

constexpr int kC    = 256;
constexpr int kNH   = 8;
constexpr int kNREG = 48;
constexpr int kB    = 4;
constexpr int kHW   = 5376;
constexpr int kQ    = kNREG + kHW;        // 5424
constexpr int kNTOK = kB * kQ;            // 21696
constexpr int kFTOK = kB * 128 * 128;     // 65536

// ---------------------------------------------------------------- init src
__global__ __launch_bounds__(256)
void k_init_src(const float* __restrict__ reg3, const float* __restrict__ reg4,
                const float* __restrict__ reg5, const float* __restrict__ res3,
                const float* __restrict__ res4, const float* __restrict__ res5,
                float* __restrict__ SRC)
{
  int idx = blockIdx.x * 256 + threadIdx.x;          // one float4
  if (idx >= kB * kQ * 64) return;
  int c4 = idx & 63;
  int t  = (idx >> 6) % kQ;
  int b  = idx / (64 * kQ);
  const float4* src;
  if (t < 16)      src = (const float4*)(reg3 + (size_t)(b * 16 + t) * kC);
  else if (t < 32) src = (const float4*)(reg4 + (size_t)(b * 16 + t - 16) * kC);
  else if (t < 48) src = (const float4*)(reg5 + (size_t)(b * 16 + t - 32) * kC);
  else {
    int u = t - 48;
    if (u < 4096)      src = (const float4*)(res3 + ((size_t)b * 4096 + u) * kC);
    else if (u < 5120) src = (const float4*)(res4 + ((size_t)b * 1024 + (u - 4096)) * kC);
    else               src = (const float4*)(res5 + ((size_t)b * 256  + (u - 5120)) * kC);
  }
  ((float4*)(SRC + ((size_t)b * kQ + t) * kC))[c4] = src[c4];
}

// ---------------------------------------------------------------- pos + ref
__global__ __launch_bounds__(256)
void k_pos_ref(float* __restrict__ POS, float* __restrict__ REF)
{
  int t = blockIdx.x;
  int c = threadIdx.x;
  if (t < kNREG) {
    POS[(size_t)t * kC + c] = 0.f;
    if (c == 0) { REF[t * 2] = 0.f; REF[t * 2 + 1] = 0.f; }
    return;
  }
  int u = t - kNREG;
  int S, base;
  if (u < 4096)      { S = 64; base = 0;    }
  else if (u < 5120) { S = 32; base = 4096; }
  else               { S = 16; base = 5120; }
  int loc = u - base;
  int ly = loc / S, lx = loc - ly * S;
  const float scale = 6.283185307179586f;
  float v, idxf;
  if (c < 128) { v = (float)(ly + 1) / ((float)S + 1e-6f) * scale; idxf = (float)(c >> 1); }
  else         { v = (float)(lx + 1) / ((float)S + 1e-6f) * scale; idxf = (float)((c - 128) >> 1); }
  float dt  = powf(10000.f, idxf * (1.f / 64.f));
  float arg = v / dt;
  POS[(size_t)t * kC + c] = (c & 1) ? cosf(arg) : sinf(arg);
  if (c == 0) {
    REF[t * 2]     = ((float)lx + 0.5f) / (float)S;
    REF[t * 2 + 1] = ((float)ly + 0.5f) / (float)S;
  }
}

// ---------------------------------------------------------------- layernorm (materialize)
__global__ __launch_bounds__(256)
void k_ln(const float* __restrict__ X, const float* __restrict__ w,
          float* __restrict__ Y, int ntok)
{
  int wave = threadIdx.x >> 6;
  int lane = threadIdx.x & 63;
  int t = blockIdx.x * 4 + wave;
  if (t >= ntok) return;
  float4 v = ((const float4*)(X + (size_t)t * kC))[lane];
  float s  = v.x + v.y + v.z + v.w;
  float ss = v.x * v.x + v.y * v.y + v.z * v.z + v.w * v.w;
#pragma unroll
  for (int o = 32; o >= 1; o >>= 1) {
    s  += __shfl_xor(s,  o, 64);
    ss += __shfl_xor(ss, o, 64);
  }
  float m   = s * (1.f / 256.f);
  float var = ss * (1.f / 256.f) - m * m;
  float r   = rsqrtf(var + 1e-6f);
  float4 wv = ((const float4*)w)[lane];
  float4 o4;
  o4.x = (v.x - m) * r * wv.x;
  o4.y = (v.y - m) * r * wv.y;
  o4.z = (v.z - m) * r * wv.z;
  o4.w = (v.w - m) * r * wv.w;
  ((float4*)(Y + (size_t)t * kC))[lane] = o4;
}

// ---------------------------------------------------------------- layernorm stats only
__global__ __launch_bounds__(256)
void k_lnstat(const float* __restrict__ X, float2* __restrict__ st, int ntok)
{
  int wave = threadIdx.x >> 6;
  int lane = threadIdx.x & 63;
  int t = blockIdx.x * 4 + wave;
  if (t >= ntok) return;
  float4 v = ((const float4*)(X + (size_t)t * kC))[lane];
  float s  = v.x + v.y + v.z + v.w;
  float ss = v.x * v.x + v.y * v.y + v.z * v.z + v.w * v.w;
#pragma unroll
  for (int o = 32; o >= 1; o >>= 1) {
    s  += __shfl_xor(s,  o, 64);
    ss += __shfl_xor(ss, o, 64);
  }
  float m   = s * (1.f / 256.f);
  float var = ss * (1.f / 256.f) - m * m;
  if (lane == 0) st[t] = make_float2(m, rsqrtf(var + 1e-6f));
}

// ---------------------------------------------------------------- q = src2 + pos
__global__ __launch_bounds__(256)
void k_addpos(const float* __restrict__ S2, const float* __restrict__ POS,
              float* __restrict__ Qb)
{
  int idx = blockIdx.x * 256 + threadIdx.x;    // float4 index
  if (idx >= kB * kQ * 64) return;
  int c4 = idx & 63;
  int t  = (idx >> 6) % kQ;
  float4 a = ((const float4*)S2)[idx];
  float4 p = ((const float4*)POS)[(size_t)t * 64 + c4];
  a.x += p.x; a.y += p.y; a.z += p.z; a.w += p.w;
  ((float4*)Qb)[idx] = a;
}

// ---------------------------------------------------------------- elementwise add
__global__ __launch_bounds__(256)
void k_add(float* __restrict__ Y, const float* __restrict__ X, int n4)
{
  int i = blockIdx.x * 256 + threadIdx.x;
  if (i >= n4) return;
  float4 a = ((float4*)Y)[i];
  float4 b = ((const float4*)X)[i];
  a.x += b.x; a.y += b.y; a.z += b.z; a.w += b.w;
  ((float4*)Y)[i] = a;
}

// ---------------------------------------------------------------- GEMM  Y = act(X @ W^T + bias) [+resid]
// X:(N,K) row-major, Wt:(M,K) row-major. 64x64 tile, BK=16, thread 4x4.
__global__ __launch_bounds__(256)
void k_gemm(const float* __restrict__ X, const float* __restrict__ Wt,
            const float* __restrict__ bias, const float* __restrict__ resid,
            const float* __restrict__ ssp, const float* __restrict__ sbp,
            float* __restrict__ Y, int N, int K, int M)
{
  __shared__ __align__(16) float As[16][64];
  __shared__ __align__(16) float Bs[16][64];
  const int tid = threadIdx.x;
  const int n0 = blockIdx.x * 64, m0 = blockIdx.y * 64;
  const int ty = tid >> 4, tx = tid & 15;
  const int lr = tid >> 2, lc = (tid & 3) << 2;
  const int nrow = n0 + lr, mrow = m0 + lr;
  const bool nok = nrow < N;
  const bool mok = mrow < M;
  const float* xp = X  + (size_t)(nok ? nrow : 0) * K + lc;
  const float* wp = Wt + (size_t)(mok ? mrow : 0) * K + lc;
  float acc[4][4] = {};
  for (int k0 = 0; k0 < K; k0 += 16) {
    float4 av = nok ? *(const float4*)(xp + k0) : make_float4(0, 0, 0, 0);
    float4 bv = mok ? *(const float4*)(wp + k0) : make_float4(0, 0, 0, 0);
    As[lc + 0][lr] = av.x; As[lc + 1][lr] = av.y; As[lc + 2][lr] = av.z; As[lc + 3][lr] = av.w;
    Bs[lc + 0][lr] = bv.x; Bs[lc + 1][lr] = bv.y; Bs[lc + 2][lr] = bv.z; Bs[lc + 3][lr] = bv.w;
    __syncthreads();
#pragma unroll
    for (int k = 0; k < 16; k++) {
      float4 a4 = *(const float4*)&As[k][ty << 2];
      float4 b4 = *(const float4*)&Bs[k][tx << 2];
      float ar[4] = {a4.x, a4.y, a4.z, a4.w};
      float br[4] = {b4.x, b4.y, b4.z, b4.w};
#pragma unroll
      for (int i = 0; i < 4; i++)
#pragma unroll
        for (int j = 0; j < 4; j++)
          acc[i][j] = fmaf(ar[i], br[j], acc[i][j]);
    }
    __syncthreads();
  }
  float ssv = 0.f, sbv = 0.f;
  if (ssp) { ssv = *ssp; sbv = *sbp; }
#pragma unroll
  for (int i = 0; i < 4; i++) {
    int n = n0 + (ty << 2) + i;
    if (n >= N) continue;
    float* yr = Y + (size_t)n * M;
    const float* rr = resid ? resid + (size_t)n * M : nullptr;
#pragma unroll
    for (int j = 0; j < 4; j++) {
      int m = m0 + (tx << 2) + j;
      if (m >= M) continue;
      float v = acc[i][j];
      if (bias) v += bias[m];
      if (ssp) { float t = fmaxf(v, 0.f); v = fmaf(ssv * t, t, sbv); }
      if (rr) v += rr[m];
      yr[m] = v;
    }
  }
}

// ---------------------------------------------------------------- repack ONE conv chunk
// in : (oc, ic, 3,3) 589824 floats  ->  out: (tap, ic, oc)
__global__ __launch_bounds__(256)
void k_repack_one(const float* __restrict__ w, float* __restrict__ wt)
{
  int i = blockIdx.x * 256 + threadIdx.x;
  if (i >= 9 * 65536) return;
  int oc  = i & 255;
  int ic  = (i >> 8) & 255;
  int tap = i >> 16;
  wt[i] = w[(size_t)oc * 2304 + ic * 9 + tap];
}

// ---------------------------------------------------------------- conv3x3 NHWC, C=256->256, SAME
// wt: (9, 256ic, 256oc). 64-pixel x 64-oc tile. If resid!=null: out = resid + conv.
__global__ __launch_bounds__(256)
void k_conv3x3(const float* __restrict__ in, const float* __restrict__ wt,
               const float* __restrict__ bias, float* __restrict__ out,
               const float* __restrict__ resid, int H, int W)
{
  __shared__ __align__(16) float As[16][64];
  __shared__ __align__(16) float Bs[16][64];
  const int tid = threadIdx.x;
  const int p0 = blockIdx.x * 64, m0 = blockIdx.y * 64;
  const int ty = tid >> 4, tx = tid & 15;
  const int lr = tid >> 2, lc = (tid & 3) << 2;
  const int hw = H * W;
  int pix = p0 + lr;
  int b = pix / hw;
  int rem = pix - b * hw;
  int py = rem / W, px = rem - py * W;
  const int bic = tid >> 4;
  const int boc = (tid & 15) << 2;
  float acc[4][4] = {};
  for (int tap = 0; tap < 9; tap++) {
    int dy = tap / 3 - 1, dx = tap - (tap / 3) * 3 - 1;
    int ny = py + dy, nx = px + dx;
    bool ok = (unsigned)ny < (unsigned)H && (unsigned)nx < (unsigned)W;
    const float* ap = in + (((size_t)b * H + (ok ? ny : 0)) * W + (ok ? nx : 0)) * kC + lc;
    const float* bp = wt + (size_t)tap * 65536 + (size_t)bic * kC + m0 + boc;
    for (int k0 = 0; k0 < kC; k0 += 16) {
      float4 av = ok ? *(const float4*)(ap + k0) : make_float4(0, 0, 0, 0);
      As[lc + 0][lr] = av.x; As[lc + 1][lr] = av.y; As[lc + 2][lr] = av.z; As[lc + 3][lr] = av.w;
      float4 bv = *(const float4*)(bp + (size_t)k0 * kC);
      *(float4*)&Bs[bic][boc] = bv;
      __syncthreads();
#pragma unroll
      for (int k = 0; k < 16; k++) {
        float4 a4 = *(const float4*)&As[k][ty << 2];
        float4 b4 = *(const float4*)&Bs[k][tx << 2];
        float ar[4] = {a4.x, a4.y, a4.z, a4.w};
        float br[4] = {b4.x, b4.y, b4.z, b4.w};
#pragma unroll
        for (int i = 0; i < 4; i++)
#pragma unroll
          for (int j = 0; j < 4; j++)
            acc[i][j] = fmaf(ar[i], br[j], acc[i][j]);
      }
      __syncthreads();
    }
  }
#pragma unroll
  for (int i = 0; i < 4; i++) {
    int p = p0 + (ty << 2) + i;
    float* yr = out + (size_t)p * kC;
    const float* rr = resid ? resid + (size_t)p * kC : nullptr;
#pragma unroll
    for (int j = 0; j < 4; j++) {
      int m = m0 + (tx << 2) + j;
      float v = acc[i][j] + bias[m];
      if (rr) v += rr[m];
      yr[m] = v;
    }
  }
}

// ---------------------------------------------------------------- bilinear 2x upsample + skip add
// out[p] = LN?(map[b*mapStride + rem*C]) + resize2x(cur)
__global__ __launch_bounds__(256)
void k_resize_add(const float* __restrict__ mapsrc, size_t mapStride,
                  const float* __restrict__ cur, size_t curStride,
                  float* __restrict__ out, int Ho, int Wo,
                  const float2* __restrict__ mstats, const float* __restrict__ mlnw)
{
  int idx = blockIdx.x * 256 + threadIdx.x;    // float4 index
  int tot = kB * Ho * Wo * 64;
  if (idx >= tot) return;
  int c4 = idx & 63;
  int p  = idx >> 6;
  int b  = p / (Ho * Wo);
  int rem = p - b * (Ho * Wo);
  int oy = rem / Wo, ox = rem - oy * Wo;
  int Hi = Ho >> 1, Wi = Wo >> 1;
  float sy = oy * 0.5f - 0.25f;
  float sx = ox * 0.5f - 0.25f;
  float fy0 = floorf(sy), fx0 = floorf(sx);
  float fy = sy - fy0, fx = sx - fx0;
  int y0 = (int)fy0, x0 = (int)fx0;
  int y0c = min(max(y0, 0), Hi - 1), y1c = min(max(y0 + 1, 0), Hi - 1);
  int x0c = min(max(x0, 0), Wi - 1), x1c = min(max(x0 + 1, 0), Wi - 1);
  const float* cb = cur + (size_t)b * curStride;
  float4 v00 = ((const float4*)(cb + ((size_t)y0c * Wi + x0c) * kC))[c4];
  float4 v01 = ((const float4*)(cb + ((size_t)y0c * Wi + x1c) * kC))[c4];
  float4 v10 = ((const float4*)(cb + ((size_t)y1c * Wi + x0c) * kC))[c4];
  float4 v11 = ((const float4*)(cb + ((size_t)y1c * Wi + x1c) * kC))[c4];
  float w00 = (1.f - fy) * (1.f - fx), w01 = (1.f - fy) * fx;
  float w10 = fy * (1.f - fx),          w11 = fy * fx;
  float4 mv = ((const float4*)(mapsrc + (size_t)b * mapStride + (size_t)rem * kC))[c4];
  if (mstats) {
    float2 st = mstats[(size_t)b * (Ho * Wo) + rem];
    float4 wv = ((const float4*)mlnw)[c4];
    mv.x = (mv.x - st.x) * st.y * wv.x;
    mv.y = (mv.y - st.x) * st.y * wv.y;
    mv.z = (mv.z - st.x) * st.y * wv.z;
    mv.w = (mv.w - st.x) * st.y * wv.w;
  }
  float4 o;
  o.x = mv.x + w00 * v00.x + w01 * v01.x + w10 * v10.x + w11 * v11.x;
  o.y = mv.y + w00 * v00.y + w01 * v01.y + w10 * v10.y + w11 * v11.y;
  o.z = mv.z + w00 * v00.z + w01 * v01.z + w10 * v10.z + w11 * v11.z;
  o.w = mv.w + w00 * v00.w + w01 * v01.w + w10 * v10.w + w11 * v11.w;
  ((float4*)(out + (size_t)p * kC))[c4] = o;
}

// ---------------------------------------------------------------- MSDA gather (softmax fused)
// 32 lanes = one (b,q,h); lane = head-dim channel.
__global__ __launch_bounds__(256)
void k_msda(const float* __restrict__ VAL, const float* __restrict__ OFF,
            const float* __restrict__ AW, const float* __restrict__ REF,
            float* __restrict__ OUT)
{
  int g  = blockIdx.x * 8 + (threadIdx.x >> 5);
  int hd = threadIdx.x & 31;
  if (g >= kNTOK * kNH) return;
  int h  = g % kNH;
  int bq = g / kNH;          // b*kQ + q
  int q  = bq % kQ;
  int b  = bq / kQ;
  float refx = REF[q * 2], refy = REF[q * 2 + 1];
  const float* offp = OFF + (size_t)g * 24;
  const float* awp  = AW  + (size_t)g * 12;
  float lg[12];
  float mx = -1e30f;
#pragma unroll
  for (int i = 0; i < 12; i++) { lg[i] = awp[i]; mx = fmaxf(mx, lg[i]); }
  float sum = 0.f;
#pragma unroll
  for (int i = 0; i < 12; i++) { lg[i] = expf(lg[i] - mx); sum += lg[i]; }
  float rs = 1.f / sum;
  const float* vb = VAL + (size_t)b * kQ * kC + h * 32 + hd;
  const int Ls[3]    = {64, 32, 16};
  const int Lbase[3] = {kNREG, kNREG + 4096, kNREG + 5120};
  float acc = 0.f;
#pragma unroll
  for (int l = 0; l < 3; l++) {
    const int S = Ls[l];
    const int base = Lbase[l];
    const float fS = (float)S;
#pragma unroll
    for (int p = 0; p < 4; p++) {
      float ox = offp[l * 8 + p * 2 + 0];
      float oy = offp[l * 8 + p * 2 + 1];
      float a  = lg[l * 4 + p] * rs;
      float locx = refx + ox / fS;
      float locy = refy + oy / fS;
      float x = locx * fS - 0.5f;
      float y = locy * fS - 0.5f;
      float x0f = floorf(x), y0f = floorf(y);
      float wx = x - x0f, wy = y - y0f;
      int x0 = (int)x0f, y0 = (int)y0f;
      float s = 0.f;
#pragma unroll
      for (int cy = 0; cy < 2; cy++) {
        int yi = y0 + cy;
        if ((unsigned)yi >= (unsigned)S) continue;
        float wyv = cy ? wy : 1.f - wy;
#pragma unroll
        for (int cx = 0; cx < 2; cx++) {
          int xi = x0 + cx;
          if ((unsigned)xi >= (unsigned)S) continue;
          float wxv = cx ? wx : 1.f - wx;
          s += wyv * wxv * vb[(size_t)(base + yi * S + xi) * kC];
        }
      }
      acc += a * s;
    }
  }
  OUT[(size_t)bq * kC + h * 32 + hd] = acc;
}

} // anonymous namespace

// ================================================================ host
extern "C" void kernel_launch(void* const* d_in, const int* in_sizes, int n_in,
                              void* d_out, int out_size, void* d_ws, size_t ws_size,
                              hipStream_t stream)
{
  (void)in_sizes; (void)n_in; (void)out_size; (void)ws_size;
  const float* res2   = (const float*)d_in[0];
  const float* res3   = (const float*)d_in[1];
  const float* res4   = (const float*)d_in[2];
  const float* res5   = (const float*)d_in[3];
  const float* reg3   = (const float*)d_in[4];
  const float* reg4   = (const float*)d_in[5];
  const float* reg5   = (const float*)d_in[6];
  const float* norm1w = (const float*)d_in[7];
  const float* norm2w = (const float*)d_in[8];
  const float* off_w  = (const float*)d_in[9];
  const float* off_b  = (const float*)d_in[10];
  const float* aw_w   = (const float*)d_in[11];
  const float* aw_b   = (const float*)d_in[12];
  const float* val_w  = (const float*)d_in[13];
  const float* val_b  = (const float*)d_in[14];
  const float* out_w  = (const float*)d_in[15];
  const float* out_b  = (const float*)d_in[16];
  const float* conv_w = (const float*)d_in[17];
  const float* conv_b = (const float*)d_in[18];
  const float* fc1_w  = (const float*)d_in[19];
  const float* fc2_w  = (const float*)d_in[20];
  const float* star_s = (const float*)d_in[21];
  const float* star_b = (const float*)d_in[22];

  // SRC and FPN live directly in d_out (final layout == working layout).
  float* SRC = (float*)d_out;                              // 5,554,176 floats
  float* FPN = (float*)d_out + (size_t)kNTOK * kC;         // 16,777,216 floats

  float* ws = (float*)d_ws;
  size_t woff = 0;
  auto alloc = [&](size_t n) -> float* {
    float* p = ws + woff;
    woff += (n + 63) & ~(size_t)63;
    return p;
  };
  float*  POS  = alloc((size_t)kQ * kC);            // 1.39M fl
  float*  REF  = alloc((size_t)kQ * 2);
  float*  SRC2 = alloc((size_t)kNTOK * kC);         // 5.55M fl
  float2* FST  = (float2*)alloc((size_t)kFTOK * 2); // fpn LN stats
  float*  CA   = alloc((size_t)kFTOK * kC);         // 16.78M fl
  float*  CB   = alloc((size_t)kFTOK * kC);         // 16.78M fl
  float*  WTs  = alloc((size_t)9 * 65536);          // one repacked conv (2.4 MB)
  // Total ws: ~41.2M floats (~165 MB).

  // Overlays (lifetimes verified against stream order):
  float* Qb    = CA;                                // q = LN(src)+pos, then MSDA out
  float* MSOUT = CA;
  float* VAL   = CB;                                // value proj
  float* OFFB  = CB + (size_t)kNTOK * kC;           // sampling offsets (kNTOK*192)
  float* AWB   = OFFB + (size_t)kNTOK * 192;        // attn logits    (kNTOK*96)

  k_init_src<<<kNTOK * 64 / 256, 256, 0, stream>>>(reg3, reg4, reg5, res3, res4, res5, SRC);
  hipMemcpyAsync(FPN, res2, (size_t)kFTOK * kC * sizeof(float), hipMemcpyDeviceToDevice, stream);
  k_pos_ref<<<kQ, 256, 0, stream>>>(POS, REF);

  auto gemm = [&](const float* X, const float* Wt, const float* bias, const float* resid,
                  const float* ssp, const float* sbp, float* Y, int N, int K, int M) {
    dim3 g((N + 63) / 64, (M + 63) / 64);
    k_gemm<<<g, 256, 0, stream>>>(X, Wt, bias, resid, ssp, sbp, Y, N, K, M);
  };

  const size_t qs = (size_t)kQ * kC;
  for (int l = 0; l < 6; l++) {
    const float* n1w = norm1w + (size_t)l * kC;
    const float* n2w = norm2w + (size_t)l * kC;
    const float* Wo = off_w + (size_t)l * 192 * kC;  const float* bo = off_b + (size_t)l * 192;
    const float* Wa = aw_w  + (size_t)l * 96 * kC;   const float* ba = aw_b  + (size_t)l * 96;
    const float* Wv = val_w + (size_t)l * kC * kC;   const float* bv = val_b + (size_t)l * kC;
    const float* Wp = out_w + (size_t)l * kC * kC;   const float* bp = out_b + (size_t)l * kC;
    const float* w1 = fc1_w + (size_t)l * 1024 * kC;
    const float* w2 = fc2_w + (size_t)l * kC * 1024;
    const float* cbb = conv_b + (size_t)l * 3 * kC;
    const float* cwl = conv_w + (size_t)l * 3 * 589824;

    // LN1: src materialized, fpn stats only (applied on the fly at the 128-level skip)
    k_ln<<<(kNTOK + 3) / 4, 256, 0, stream>>>(SRC, n1w, SRC2, kNTOK);
    k_lnstat<<<(kFTOK + 3) / 4, 256, 0, stream>>>(FPN, FST, kFTOK);

    // MSDA
    gemm(SRC2, Wv, bv, nullptr, nullptr, nullptr, VAL, kNTOK, kC, kC);
    k_addpos<<<kNTOK * 64 / 256, 256, 0, stream>>>(SRC2, POS, Qb);
    gemm(Qb, Wo, bo, nullptr, nullptr, nullptr, OFFB, kNTOK, kC, 192);
    gemm(Qb, Wa, ba, nullptr, nullptr, nullptr, AWB,  kNTOK, kC, 96);
    k_msda<<<kNTOK * kNH / 8, 256, 0, stream>>>(VAL, OFFB, AWB, REF, MSOUT);
    gemm(MSOUT, Wp, bp, nullptr, nullptr, nullptr, SRC2, kNTOK, kC, kC);

    // FPN chain: 16 -> 32 -> 64 -> 128, conv3x3 after each upsample+skip.
    // Last conv fuses the FPN residual (FPN = FPN + conv(...)).
    k_resize_add<<<kB * 32 * 32 * 64 / 256, 256, 0, stream>>>(
        SRC2 + (size_t)(kNREG + 4096) * kC, qs, SRC2 + (size_t)(kNREG + 5120) * kC, qs,
        CA, 32, 32, nullptr, nullptr);
    k_repack_one<<<9 * 65536 / 256, 256, 0, stream>>>(cwl + 0 * 589824, WTs);
    k_conv3x3<<<dim3(kB * 32 * 32 / 64, 4), 256, 0, stream>>>(CA, WTs, cbb + 0 * kC, CB, nullptr, 32, 32);
    k_resize_add<<<kB * 64 * 64 * 64 / 256, 256, 0, stream>>>(
        SRC2 + (size_t)kNREG * kC, qs, CB, (size_t)32 * 32 * kC, CA, 64, 64, nullptr, nullptr);
    k_repack_one<<<9 * 65536 / 256, 256, 0, stream>>>(cwl + 1 * 589824, WTs);
    k_conv3x3<<<dim3(kB * 64 * 64 / 64, 4), 256, 0, stream>>>(CA, WTs, cbb + 1 * kC, CB, nullptr, 64, 64);
    k_resize_add<<<kB * 128 * 128 * 64 / 256, 256, 0, stream>>>(
        FPN, (size_t)128 * 128 * kC, CB, (size_t)64 * 64 * kC, CA, 128, 128, FST, n1w);
    k_repack_one<<<9 * 65536 / 256, 256, 0, stream>>>(cwl + 2 * 589824, WTs);
    k_conv3x3<<<dim3(kB * 128 * 128 / 64, 4), 256, 0, stream>>>(CA, WTs, cbb + 2 * kC, FPN, FPN, 128, 128);

    // src residual
    k_add<<<kNTOK * 64 / 256, 256, 0, stream>>>(SRC, SRC2, kNTOK * 64);

    // MLP on src (hidden in CA, 16384-token chunks)
    k_ln<<<(kNTOK + 3) / 4, 256, 0, stream>>>(SRC, n2w, SRC2, kNTOK);
    for (int c0 = 0; c0 < kNTOK; c0 += 16384) {
      int n = kNTOK - c0; if (n > 16384) n = 16384;
      gemm(SRC2 + (size_t)c0 * kC, w1, nullptr, nullptr, star_s + l, star_b + l, CA, n, kC, 1024);
      gemm(CA, w2, nullptr, SRC + (size_t)c0 * kC, nullptr, nullptr, SRC + (size_t)c0 * kC, n, 1024, kC);
    }
    // MLP on fpn (LN into CB, hidden in CA)
    k_ln<<<(kFTOK + 3) / 4, 256, 0, stream>>>(FPN, n2w, CB, kFTOK);
    for (int c0 = 0; c0 < kFTOK; c0 += 16384) {
      gemm(CB + (size_t)c0 * kC, w1, nullptr, nullptr, star_s + l, star_b + l, CA, 16384, kC, 1024);
      gemm(CA, w2, nullptr, FPN + (size_t)c0 * kC, nullptr, nullptr, FPN + (size_t)c0 * kC, 16384, 1024, kC);
    }
  }
  // SRC and FPN are d_out — nothing to copy.
}